// Round 3
// baseline (99.761 us; speedup 1.0000x reference)
//
#include <hip/hip_runtime.h>
#include <math.h>

// Fuzzy LeNet-5, Yager p=1 == Lukasiewicz: T(a,b)=max(0,a+b-1).
// Fuzzy conv == max-plus conv: out = relu(max_{c,kh,kw}(x+w) - 1).
// maxpool2 folds into the conv via dilated weights:
//   W'[uy][ux] = max_{dy,dx in {0,1}, uy-dy,ux-dx in [0,5)} w[uy-dy][ux-dx]
// Single fused kernel, one block per image (launch overhead ~ kernel time at
// this size; 3-kernel version measured slower end-to-end). L1 is strip-mined:
// each thread computes a 7-px row strip, amortizing LDS row loads 7x.

#define NT 256
#define ROWS 34                // padded input row stride (floats)
#define PLANE (32 * ROWS)

__global__ __launch_bounds__(NT) void fused_lenet(
    const float* __restrict__ x,   // [B,3,32,32]
    const float* __restrict__ w1,  // [6,3,5,5]
    const float* __restrict__ w2,  // [16,6,5,5]
    const float* __restrict__ w3,  // [120,16,5,5]
    const float* __restrict__ wd,  // [120,84]
    const float* __restrict__ wf,  // [84,10]
    const float* __restrict__ bfv, // [10]
    float* __restrict__ out)       // [B,10]
{
    const int img = blockIdx.x;
    const int tid = threadIdx.x;

    __shared__ float s_in[3 * PLANE];    // padded image
    __shared__ float s_w1d[6 * 108];     // dilated w1 [oc][c][uy][ux(6)]
    __shared__ float s_w2d[16 * 216];    // dilated w2 [oc][c][uy][ux(6)]
    __shared__ float s_a1[6 * 196];      // L1 pooled [c][14][14]
    __shared__ float s_a2[400];          // L2 pooled [16][5][5]
    __shared__ float s_a3[120];
    __shared__ float s_a4[84];
    __shared__ float s_logits[10];
    __shared__ float s_red[2];

    // ---- Phase A: stage image (padded rows) + dilate both conv weights
    const float2* src = (const float2*)(x + img * 3072);
    for (int i = tid; i < 1536; i += NT) {
        const int c = i >> 9, rem = i & 511, r = rem >> 4, col2 = rem & 15;
        ((float2*)s_in)[c * (PLANE / 2) + r * (ROWS / 2) + col2] = src[i];
    }
    for (int e = tid; e < 648; e += NT) {             // w1: 6*3*36
        const int oc = e / 108, u = e - oc * 108;
        const int c = u / 36, v = u - c * 36;
        const int r = v / 6, col = v - r * 6;
        const float* wb = w1 + oc * 75 + c * 25;
        float m = -1e30f;
        #pragma unroll
        for (int dy = 0; dy < 2; ++dy) {
            const int kh = r - dy;
            if ((unsigned)kh > 4u) continue;
            #pragma unroll
            for (int dx = 0; dx < 2; ++dx) {
                const int kw = col - dx;
                if ((unsigned)kw > 4u) continue;
                m = fmaxf(m, wb[kh * 5 + kw]);
            }
        }
        s_w1d[e] = m;
    }
    for (int e = tid; e < 3456; e += NT) {            // w2: 16*6*36
        const int oc = e / 216, u = e - oc * 216;
        const int c = u / 36, v = u - c * 36;
        const int r = v / 6, col = v - r * 6;
        const float* wb = w2 + oc * 150 + c * 25;
        float m = -1e30f;
        #pragma unroll
        for (int dy = 0; dy < 2; ++dy) {
            const int kh = r - dy;
            if ((unsigned)kh > 4u) continue;
            #pragma unroll
            for (int dx = 0; dx < 2; ++dx) {
                const int kw = col - dx;
                if ((unsigned)kw > 4u) continue;
                m = fmaxf(m, wb[kh * 5 + kw]);
            }
        }
        s_w2d[e] = m;
    }
    __syncthreads();

    // ---- Phase B: L1 [3,32,32] -> [6,14,14], strip of 7 px per thread
    // task: oc in [0,6), py in [0,14), s in {0,1}  (px = 7s..7s+6)
    if (tid < 168) {
        const int oc = tid / 28;
        const int r = tid - oc * 28;
        const int py = r >> 1, s = r & 1;
        float acc[7];
        #pragma unroll
        for (int j = 0; j < 7; ++j) acc[j] = -1e30f;
        for (int c = 0; c < 3; ++c) {
            #pragma unroll
            for (int uy = 0; uy < 6; ++uy) {
                const float* xr = s_in + c * PLANE + (2 * py + uy) * ROWS + 14 * s;
                float xv[18];
                #pragma unroll
                for (int i2 = 0; i2 < 9; ++i2)
                    ((float2*)xv)[i2] = ((const float2*)xr)[i2];
                const float* wr = s_w1d + oc * 108 + c * 36 + uy * 6;
                float wv[6];
                #pragma unroll
                for (int i2 = 0; i2 < 3; ++i2)
                    ((float2*)wv)[i2] = ((const float2*)wr)[i2];
                #pragma unroll
                for (int j = 0; j < 7; ++j) {
                    #pragma unroll
                    for (int ux = 0; ux < 6; ++ux)
                        acc[j] = fmaxf(acc[j], xv[2 * j + ux] + wv[ux]);
                }
            }
        }
        #pragma unroll
        for (int j = 0; j < 7; ++j)
            s_a1[oc * 196 + py * 14 + 7 * s + j] = fmaxf(acc[j] - 1.0f, 0.0f);
    }
    __syncthreads();

    // ---- Phase C: L2 [6,14,14] -> [16,5,5]
    for (int idx = tid; idx < 400; idx += NT) {
        const int oc = idx / 25, pix = idx - oc * 25;
        const int py = pix / 5, px = pix - py * 5;
        const float* wo = s_w2d + oc * 216;
        float m = -1e30f;
        for (int c = 0; c < 6; ++c) {
            const float* xc = s_a1 + c * 196 + 2 * py * 14 + 2 * px;
            const float* wc = wo + c * 36;
            #pragma unroll
            for (int uy = 0; uy < 6; ++uy) {
                const float2 x0 = *(const float2*)(xc + uy * 14);
                const float2 x1 = *(const float2*)(xc + uy * 14 + 2);
                const float2 x2 = *(const float2*)(xc + uy * 14 + 4);
                const float2 w0 = *(const float2*)(wc + uy * 6);
                const float2 w1v = *(const float2*)(wc + uy * 6 + 2);
                const float2 w2v = *(const float2*)(wc + uy * 6 + 4);
                m = fmaxf(m, fmaxf(fmaxf(x0.x + w0.x, x0.y + w0.y),
                          fmaxf(fmaxf(x1.x + w1v.x, x1.y + w1v.y),
                                fmaxf(x2.x + w2v.x, x2.y + w2v.y))));
            }
        }
        s_a2[idx] = fmaxf(m - 1.0f, 0.0f);
    }
    __syncthreads();

    // ---- Phase D: L3 [16,5,5] -> [120], 2 threads per output, w3 from L2
    if (tid < 240) {
        const int o = tid >> 1, h = tid & 1;
        const float4* wv = (const float4*)(w3 + o * 400 + h * 200);
        const float4* av = (const float4*)(s_a2 + h * 200);
        float m = -1e30f;
        #pragma unroll 5
        for (int l = 0; l < 50; ++l) {
            const float4 w = wv[l];
            const float4 a = av[l];
            m = fmaxf(m, fmaxf(fmaxf(a.x + w.x, a.y + w.y),
                               fmaxf(a.z + w.z, a.w + w.w)));
        }
        m = fmaxf(m, __shfl_xor(m, 1));
        if (h == 0) s_a3[o] = fmaxf(m - 1.0f, 0.0f);
    }
    __syncthreads();

    // ---- Dense [120]->[84] + tanh
    if (tid < 84) {
        float acc = 0.0f;
        for (int i = 0; i < 120; ++i)
            acc = fmaf(s_a3[i], wd[i * 84 + tid], acc);
        s_a4[tid] = tanhf(acc);
    }
    __syncthreads();

    // ---- FC [84]->[10] + bias
    if (tid < 10) {
        float acc = bfv[tid];
        for (int i = 0; i < 84; ++i)
            acc = fmaf(s_a4[i], wf[i * 10 + tid], acc);
        s_logits[tid] = acc;
    }
    __syncthreads();

    // ---- log_softmax
    if (tid == 0) {
        float m = s_logits[0];
        for (int i = 1; i < 10; ++i) m = fmaxf(m, s_logits[i]);
        float s = 0.0f;
        for (int i = 0; i < 10; ++i) s += expf(s_logits[i] - m);
        s_red[0] = m;
        s_red[1] = logf(s);
    }
    __syncthreads();
    if (tid < 10)
        out[img * 10 + tid] = s_logits[tid] - s_red[0] - s_red[1];
}

extern "C" void kernel_launch(void* const* d_in, const int* in_sizes, int n_in,
                              void* d_out, int out_size, void* d_ws, size_t ws_size,
                              hipStream_t stream) {
    const float* x   = (const float*)d_in[0];
    const float* w1  = (const float*)d_in[1];
    const float* w2  = (const float*)d_in[2];
    const float* w3  = (const float*)d_in[3];
    const float* wd  = (const float*)d_in[4];
    const float* wf  = (const float*)d_in[5];
    const float* bfv = (const float*)d_in[6];
    float* out = (float*)d_out;

    const int B = in_sizes[0] / (3 * 32 * 32);
    fused_lenet<<<dim3(B), dim3(NT), 0, stream>>>(
        x, w1, w2, w3, wd, wf, bfv, out);
}

// Round 4
// 94.510 us; speedup vs baseline: 1.0556x; 1.0556x over previous
//
#include <hip/hip_runtime.h>
#include <math.h>

// Fuzzy LeNet-5, Yager p=1 == Lukasiewicz: T(a,b)=max(0,a+b-1).
// Fuzzy conv == max-plus conv: out = relu(max_{c,kh,kw}(x+w) - 1).
// maxpool2 folds into the conv via dilated 6x6 weights:
//   W'[uy][ux] = max_{dy,dx in {0,1}, uy-dy,ux-dx in [0,5)} w[uy-dy][ux-dx]
// R3 post-mortem: single fused kernel = 41 us, latency-bound (1 wave/SIMD,
// barrier-separated phases). This round: 3 kernels, wide grids, NO activation
// LDS staging (global reads ride L1/L2), LDS only for dilated weights
// (broadcast reads), term-parallel head with 8 waves/block.

// ---------- K1: [B,3,32,32] -> [B,6,14,14], grid B*6 x 256 ----------
__global__ __launch_bounds__(256) void k1_conv1(
    const float* __restrict__ x, const float* __restrict__ w1,
    float* __restrict__ a1)
{
    const int bx = blockIdx.x;
    const int img = bx / 6;
    const int oc = bx - img * 6;
    const int tid = threadIdx.x;

    __shared__ float s_w[108];  // dilated [c][uy][ux(6)]

    if (tid < 108) {
        const int c = tid / 36, v = tid - c * 36;
        const int r = v / 6, col = v - r * 6;
        const float* wb = w1 + oc * 75 + c * 25;
        float m = -1e30f;
        #pragma unroll
        for (int dy = 0; dy < 2; ++dy) {
            const int kh = r - dy;
            if ((unsigned)kh > 4u) continue;
            #pragma unroll
            for (int dx = 0; dx < 2; ++dx) {
                const int kw = col - dx;
                if ((unsigned)kw > 4u) continue;
                m = fmaxf(m, wb[kh * 5 + kw]);
            }
        }
        s_w[tid] = m;
    }
    __syncthreads();

    if (tid < 196) {
        const int py = tid / 14, px = tid - py * 14;
        const float* xb = x + img * 3072 + 2 * py * 32 + 2 * px;
        float m = -1e30f;
        for (int c = 0; c < 3; ++c) {
            const float* xc = xb + c * 1024;
            const float* wc = s_w + c * 36;
            #pragma unroll
            for (int uy = 0; uy < 6; ++uy) {
                const float2 x0 = *(const float2*)(xc + uy * 32);
                const float2 x1 = *(const float2*)(xc + uy * 32 + 2);
                const float2 x2 = *(const float2*)(xc + uy * 32 + 4);
                const float2 w0 = *(const float2*)(wc + uy * 6);
                const float2 w1v = *(const float2*)(wc + uy * 6 + 2);
                const float2 w2v = *(const float2*)(wc + uy * 6 + 4);
                m = fmaxf(m, fmaxf(fmaxf(x0.x + w0.x, x0.y + w0.y),
                          fmaxf(fmaxf(x1.x + w1v.x, x1.y + w1v.y),
                                fmaxf(x2.x + w2v.x, x2.y + w2v.y))));
            }
        }
        a1[img * 1176 + oc * 196 + tid] = fmaxf(m - 1.0f, 0.0f);
    }
}

// ---------- K2: [B,6,14,14] -> [B,16,5,5], grid B*4 x 128 ----------
__global__ __launch_bounds__(128) void k2_conv2(
    const float* __restrict__ a1, const float* __restrict__ w2,
    float* __restrict__ a2)
{
    const int bx = blockIdx.x;
    const int img = bx >> 2;
    const int g = bx & 3;
    const int tid = threadIdx.x;

    __shared__ float s_w[4 * 216];  // dilated [ocl][c][uy][ux(6)]

    for (int e = tid; e < 864; e += 128) {
        const int ocl = e / 216, u = e - ocl * 216;
        const int c = u / 36, v = u - c * 36;
        const int r = v / 6, col = v - r * 6;
        const float* wb = w2 + (g * 4 + ocl) * 150 + c * 25;
        float m = -1e30f;
        #pragma unroll
        for (int dy = 0; dy < 2; ++dy) {
            const int kh = r - dy;
            if ((unsigned)kh > 4u) continue;
            #pragma unroll
            for (int dx = 0; dx < 2; ++dx) {
                const int kw = col - dx;
                if ((unsigned)kw > 4u) continue;
                m = fmaxf(m, wb[kh * 5 + kw]);
            }
        }
        s_w[e] = m;
    }
    __syncthreads();

    if (tid < 100) {
        const int ocl = tid / 25, pix = tid - ocl * 25;
        const int py = pix / 5, px = pix - py * 5;
        const float* xb = a1 + img * 1176 + 2 * py * 14 + 2 * px;
        float m = -1e30f;
        for (int c = 0; c < 6; ++c) {
            const float* xc = xb + c * 196;
            const float* wc = s_w + ocl * 216 + c * 36;
            #pragma unroll
            for (int uy = 0; uy < 6; ++uy) {
                const float2 x0 = *(const float2*)(xc + uy * 14);
                const float2 x1 = *(const float2*)(xc + uy * 14 + 2);
                const float2 x2 = *(const float2*)(xc + uy * 14 + 4);
                const float2 w0 = *(const float2*)(wc + uy * 6);
                const float2 w1v = *(const float2*)(wc + uy * 6 + 2);
                const float2 w2v = *(const float2*)(wc + uy * 6 + 4);
                m = fmaxf(m, fmaxf(fmaxf(x0.x + w0.x, x0.y + w0.y),
                          fmaxf(fmaxf(x1.x + w1v.x, x1.y + w1v.y),
                                fmaxf(x2.x + w2v.x, x2.y + w2v.y))));
            }
        }
        a2[img * 400 + (g * 4 + ocl) * 25 + pix] = fmaxf(m - 1.0f, 0.0f);
    }
}

// ---------- K3: head, grid B x 512 ----------
__global__ __launch_bounds__(512) void k3_head(
    const float* __restrict__ a2, const float* __restrict__ w3,
    const float* __restrict__ wd, const float* __restrict__ wf,
    const float* __restrict__ bfv, float* __restrict__ out)
{
    const int img = blockIdx.x;
    const int tid = threadIdx.x;

    __shared__ float s_a2[400];
    __shared__ float s_a3[120];
    __shared__ float s_a4[84];
    __shared__ float s_logits[10];
    __shared__ float s_red[2];

    if (tid < 100)
        ((float4*)s_a2)[tid] = ((const float4*)(a2 + img * 400))[tid];
    __syncthreads();

    // L3: 4 threads per output, 100 terms each (25 float4), shuffle-max
    if (tid < 480) {
        const int o = tid >> 2, q = tid & 3;
        const float4* wv = (const float4*)(w3 + o * 400 + q * 100);
        const float4* av = (const float4*)(s_a2 + q * 100);
        float m = -1e30f;
        #pragma unroll 5
        for (int l = 0; l < 25; ++l) {
            const float4 w = wv[l];
            const float4 a = av[l];
            m = fmaxf(m, fmaxf(fmaxf(a.x + w.x, a.y + w.y),
                               fmaxf(a.z + w.z, a.w + w.w)));
        }
        m = fmaxf(m, __shfl_xor(m, 1));
        m = fmaxf(m, __shfl_xor(m, 2));
        if (q == 0) s_a3[o] = fmaxf(m - 1.0f, 0.0f);
    }
    __syncthreads();

    // Dense [120]->[84] + tanh: 2 threads per output, 60 terms each
    if (tid < 168) {
        const int o = tid >> 1, h = tid & 1;
        float acc = 0.0f;
        #pragma unroll 4
        for (int i = 0; i < 60; ++i) {
            const int k = h * 60 + i;
            acc = fmaf(s_a3[k], wd[k * 84 + o], acc);
        }
        acc += __shfl_xor(acc, 1);
        if (h == 0) s_a4[o] = tanhf(acc);
    }
    __syncthreads();

    // FC [84]->[10] + bias
    if (tid < 10) {
        float acc = bfv[tid];
        for (int i = 0; i < 84; ++i)
            acc = fmaf(s_a4[i], wf[i * 10 + tid], acc);
        s_logits[tid] = acc;
    }
    __syncthreads();

    if (tid == 0) {
        float m = s_logits[0];
        for (int i = 1; i < 10; ++i) m = fmaxf(m, s_logits[i]);
        float s = 0.0f;
        for (int i = 0; i < 10; ++i) s += expf(s_logits[i] - m);
        s_red[0] = m;
        s_red[1] = logf(s);
    }
    __syncthreads();
    if (tid < 10)
        out[img * 10 + tid] = s_logits[tid] - s_red[0] - s_red[1];
}

extern "C" void kernel_launch(void* const* d_in, const int* in_sizes, int n_in,
                              void* d_out, int out_size, void* d_ws, size_t ws_size,
                              hipStream_t stream) {
    const float* x   = (const float*)d_in[0];
    const float* w1  = (const float*)d_in[1];
    const float* w2  = (const float*)d_in[2];
    const float* w3  = (const float*)d_in[3];
    const float* wd  = (const float*)d_in[4];
    const float* wf  = (const float*)d_in[5];
    const float* bfv = (const float*)d_in[6];
    float* out = (float*)d_out;

    const int B = in_sizes[0] / (3 * 32 * 32);
    float* a1 = (float*)d_ws;             // [B,6,14,14]
    float* a2 = a1 + (size_t)B * 1176;    // [B,16,5,5]

    k1_conv1<<<dim3(B * 6), dim3(256), 0, stream>>>(x, w1, a1);
    k2_conv2<<<dim3(B * 4), dim3(128), 0, stream>>>(a1, w2, a2);
    k3_head <<<dim3(B),     dim3(512), 0, stream>>>(a2, w3, wd, wf, bfv, out);
}